// Round 2
// baseline (256.581 us; speedup 1.0000x reference)
//
#include <hip/hip_runtime.h>
#include <math.h>

// NoisyTopkRouter: B=8,S=4096,D=1024,E=64,k=2  (M=32768 tokens)
// R7: 4 fat waves/block (256 thr), each wave = 64tok x 32exp (2 MFMA tiles).
//  - A: reg-staged (2x float4/thread), fp32->fp16 hi/lo split ONCE at stage,
//    ds_write into 128B rows [hi c0-3 | lo c4-7], chunk XOR-swizzled by row&7.
//  - B: unchanged pre-split swizzled tile images (prep_B) + linear global_load_lds.
//  - dbuf 2x24KB (A 8K + B 16K), 3 blocks/CU; one barrier per K-tile.
//  - fp16x3 math (C = Ah*Bh + (Ah*Bl + Al*Bh)/2048), identical accumulation
//    order per accumulator -> bit-identical to R5/R6 (absmax 0.00390625).
//  - epilogue: merged max/argmax#1 (18 reduce rounds vs 24), math otherwise verbatim.

#define DIM 1024
#define NEXP 64
#define CS 132
#define LOSCALE 2048.0f
#define INV_LOSCALE (1.0f / 2048.0f)
#define ABUF 8192
#define BUFSZ 24576   // A 8KB + B 16KB per buffer

using half8v   = __attribute__((ext_vector_type(8)))  _Float16;
using floatx16 = __attribute__((ext_vector_type(16))) float;

#define MFMA32(a, b, c) __builtin_amdgcn_mfma_f32_32x32x16_f16((a), (b), (c), 0, 0, 0)

__device__ inline void gll16(const void* g, void* l) {
    __builtin_amdgcn_global_load_lds(
        (const __attribute__((address_space(1))) unsigned int*)g,
        (__attribute__((address_space(3))) unsigned int*)l, 16, 0, 0);
}

// ---------------- prep: split weights to fp16 hi/lo, swizzled tile images ----------
__global__ __launch_bounds__(512)
void prep_B(const float* __restrict__ Wl, const float* __restrict__ Wn,
            _Float16* __restrict__ Bp)
{
    const int idx = blockIdx.x * 512 + threadIdx.x;   // 16384 threads
    const int r  = idx >> 7;        // expert row 0..127 (0..63 = Wl, 64..127 = Wn)
    const int c2 = idx & 127;       // 8-float chunk across K=1024
    const float* W = (r < 64) ? (Wl + (size_t)r * DIM) : (Wn + (size_t)(r - 64) * DIM);
    float f[8];
    *(float4*)(f)     = *(const float4*)(W + c2 * 8);
    *(float4*)(f + 4) = *(const float4*)(W + c2 * 8 + 4);
    half8v hi, lo;
#pragma unroll
    for (int i = 0; i < 8; i++) {
        _Float16 hh = (_Float16)f[i];
        hi[i] = hh;
        lo[i] = (_Float16)((f[i] - (float)hh) * LOSCALE);
    }
    const int t = c2 >> 2, cf = c2 & 3, sw = r & 7;
    _Float16* base = Bp + ((size_t)t * 128 + r) * 64;
    *(half8v*)(base + ((cf ^ sw) << 3))       = hi;   // hi chunks 0..3
    *(half8v*)(base + (((4 | cf) ^ sw) << 3)) = lo;   // lo chunks 4..7
}

// ---------------- main fused kernel ------------------------------------------------
__global__ __launch_bounds__(256, 3)
void router_fused(const float* __restrict__ h, const _Float16* __restrict__ Bp,
                  const float* __restrict__ bl, const float* __restrict__ bn,
                  const float* __restrict__ noise,
                  float* __restrict__ outR, float* __restrict__ outIx,
                  float* __restrict__ outF)
{
    __shared__ __align__(16) char lds_raw[2 * BUFSZ];   // 49152 B; Cs needs 33792

    const int tid   = threadIdx.x;           // 0..255
    const int wv    = tid >> 6;              // 0..3
    const int lane  = tid & 63;
    const int row31 = lane & 31;
    const int oct   = lane >> 5;
    const int expg  = wv * 32;               // 0,32,64,96
    const int tok0  = blockIdx.x * 64;

    // ---- A staging: thread -> row rS, float-group gS (8 floats of the 32-K tile) ----
    const int rS = tid >> 2, gS = tid & 3;
    const float* aSrc = h + (size_t)(tok0 + rS) * DIM + gS * 8;
    const int aWrow = rS * 128;
    const int wHi = ((gS ^ (rS & 7)) << 4);
    const int wLo = (((4 | gS) ^ (rS & 7)) << 4);

    // ---- B staging: 4x gll16 per thread (16KB/tile, linear dest) ----
    const _Float16* bSrc = Bp + tid * 8;
    char* dB = lds_raw + ABUF + (tid << 4);

    // ---- fragment offsets (128B rows, 16B-chunk XOR swizzle) ----
    const int rowA0 = row31 * 128;           // token rows 0..31
    const int rowA1 = rowA0 + 32 * 128;      // token rows 32..63
    const int rowB  = ABUF + (expg + row31) * 128;
    const int swA = (row31 & 7) << 4;        // same for rows r and r+32
    const int swB = ((expg + row31) & 7) << 4;

    floatx16 acc1_0, acc2_0, acc1_1, acc2_1;
#pragma unroll
    for (int i = 0; i < 16; i++) { acc1_0[i] = 0.f; acc2_0[i] = 0.f;
                                   acc1_1[i] = 0.f; acc2_1[i] = 0.f; }

#define CVTW(dst) do {                                                         \
        float f_[8] = {a0v.x, a0v.y, a0v.z, a0v.w, a1v.x, a1v.y, a1v.z, a1v.w};\
        half8v hi_, lo_;                                                       \
        _Pragma("unroll")                                                      \
        for (int i_ = 0; i_ < 8; i_++) {                                       \
            _Float16 hh_ = (_Float16)f_[i_];                                   \
            hi_[i_] = hh_;                                                     \
            lo_[i_] = (_Float16)((f_[i_] - (float)hh_) * LOSCALE);             \
        }                                                                      \
        *(half8v*)((dst) + aWrow + wHi) = hi_;                                 \
        *(half8v*)((dst) + aWrow + wLo) = lo_;                                 \
    } while (0)

#define ISSUE_B(tt) do {                                                       \
        char* db_ = dB + ((tt) & 1) * BUFSZ;                                   \
        const _Float16* bs_ = bSrc + (size_t)(tt) * 8192;                      \
        gll16(bs_,        db_);                                                \
        gll16(bs_ + 2048, db_ + 4096);                                         \
        gll16(bs_ + 4096, db_ + 8192);                                         \
        gll16(bs_ + 6144, db_ + 12288);                                        \
    } while (0)

    // ---- prologue: A(0)->buf0, B(0)->buf0, A(1)->regs ----
    float4 a0v = *(const float4*)(aSrc);
    float4 a1v = *(const float4*)(aSrc + 4);
    ISSUE_B(0);
    CVTW(lds_raw);
    a0v = *(const float4*)(aSrc + 32);
    a1v = *(const float4*)(aSrc + 36);
    __syncthreads();                         // drains B(0) vmcnt + A(0) ds_writes

    // ---- K loop: compute t from buf[t&1]; stage A(t+1),B(t+1) into buf[(t+1)&1] ----
    for (int t = 0; t < 32; t++) {
        char* nbuf = lds_raw + ((t + 1) & 1) * BUFSZ;
        if (t < 31) {
            CVTW(nbuf);                      // A(t+1) regs -> LDS (loaded last iter)
            ISSUE_B(t + 1);                  // B(t+1) gll
        }
        if (t < 30) {                        // A(t+2) -> regs
            a0v = *(const float4*)(aSrc + 32 * (t + 2));
            a1v = *(const float4*)(aSrc + 32 * (t + 2) + 4);
        }
        const char* base = lds_raw + (t & 1) * BUFSZ;
#pragma unroll
        for (int ks = 0; ks < 2; ks++) {
            const int hc = (ks * 2 + oct) << 4;        // hi chunk byte offset
            const half8v aH0 = *(const half8v*)(base + rowA0 + (hc ^ swA));
            const half8v aL0 = *(const half8v*)(base + rowA0 + ((64 | hc) ^ swA));
            const half8v aH1 = *(const half8v*)(base + rowA1 + (hc ^ swA));
            const half8v aL1 = *(const half8v*)(base + rowA1 + ((64 | hc) ^ swA));
            const half8v bH  = *(const half8v*)(base + rowB + (hc ^ swB));
            const half8v bL  = *(const half8v*)(base + rowB + ((64 | hc) ^ swB));
            acc1_0 = MFMA32(aH0, bH, acc1_0);
            acc2_0 = MFMA32(aH0, bL, acc2_0);
            acc2_0 = MFMA32(aL0, bH, acc2_0);
            acc1_1 = MFMA32(aH1, bH, acc1_1);
            acc2_1 = MFMA32(aH1, bL, acc2_1);
            acc2_1 = MFMA32(aL1, bH, acc2_1);
        }
        __syncthreads();                     // vmcnt(0)+lgkmcnt(0): t+1 staged
    }
#undef ISSUE_B
#undef CVTW

    // ---- Cs overlay: C layout col=lane&31, row=(reg&3)+8*(reg>>2)+4*oct ----
    float* Cs = (float*)lds_raw;
#pragma unroll
    for (int i = 0; i < 16; i++) {
        const int rowt = (i & 3) + 8 * (i >> 2) + 4 * oct;
        Cs[rowt * CS + expg + row31]        = acc1_0[i] + acc2_0[i] * INV_LOSCALE;
        Cs[(32 + rowt) * CS + expg + row31] = acc1_1[i] + acc2_1[i] * INV_LOSCALE;
    }
    __syncthreads();

    // ---- fused epilogue: lane = expert; 16 tokens per wave ----
    const float blv = bl[lane];
    const float bnv = bn[lane];

    for (int t = wv; t < 64; t += 4) {
        const int gt = tok0 + t;
        float xr = Cs[t * CS + lane] + blv;
        float xf = Cs[t * CS + 64 + lane] + bnv;
        float nz = noise[(size_t)gt * NEXP + lane];

        // softplus (matches jax.nn.softplus)
        float stdv = fmaxf(xf, 0.f) + log1pf(expf(-fabsf(xf)));
        float noisy = fmaf(nz, stdv, xr);

        // merged max + argmax#1 (ties -> lowest index, matching lax.top_k)
        float v = noisy; int idx = lane;
#pragma unroll
        for (int o = 32; o > 0; o >>= 1) {
            float ov = __shfl_xor(v, o, 64);
            int   oi = __shfl_xor(idx, o, 64);
            if (ov > v || (ov == v && oi < idx)) { v = ov; idx = oi; }
        }
        const float v1 = v; const int i1 = idx;

        // full softmax over 64 lanes (max == v1)
        float p = expf(noisy - v1);
        float s = p;
#pragma unroll
        for (int o = 32; o > 0; o >>= 1) s += __shfl_xor(s, o, 64);
        float fullp = p / s;

        // argmax #2
        v = (lane == i1) ? -INFINITY : noisy; idx = lane;
#pragma unroll
        for (int o = 32; o > 0; o >>= 1) {
            float ov = __shfl_xor(v, o, 64);
            int   oi = __shfl_xor(idx, o, 64);
            if (ov > v || (ov == v && oi < idx)) { v = ov; idx = oi; }
        }
        const float v2 = v; const int i2 = idx;

        // sparse softmax over {i1,i2}
        float e2 = expf(v2 - v1);
        float den = 1.f + e2;
        float routep = (lane == i1) ? (1.f / den) : ((lane == i2) ? (e2 / den) : 0.f);

        outR[(size_t)gt * NEXP + lane] = routep;
        outF[(size_t)gt * NEXP + lane] = fullp;
        if (lane == 0) {
            outIx[(size_t)gt * 2 + 0] = (float)i1;
            outIx[(size_t)gt * 2 + 1] = (float)i2;
        }
    }
}

extern "C" void kernel_launch(void* const* d_in, const int* in_sizes, int n_in,
                              void* d_out, int out_size, void* d_ws, size_t ws_size,
                              hipStream_t stream) {
    const float* h     = (const float*)d_in[0];
    const float* Wl    = (const float*)d_in[1];
    const float* bl    = (const float*)d_in[2];
    const float* Wn    = (const float*)d_in[3];
    const float* bn    = (const float*)d_in[4];
    const float* noise = (const float*)d_in[5];
    float* out = (float*)d_out;

    const int M = in_sizes[0] / DIM;                 // 32768
    float* outR  = out;                              // [M,64]
    float* outIx = out + (size_t)M * NEXP;           // [M,2]
    float* outF  = outIx + (size_t)M * 2;            // [M,64]

    _Float16* Bp = (_Float16*)d_ws;                  // 512 KiB tile images

    prep_B<<<32, 512, 0, stream>>>(Wl, Wn, Bp);
    router_fused<<<M / 64, 256, 0, stream>>>(h, Bp, bl, bn, noise, outR, outIx, outF);
}

// Round 3
// 253.444 us; speedup vs baseline: 1.0124x; 1.0124x over previous
//
#include <hip/hip_runtime.h>
#include <math.h>

// NoisyTopkRouter: B=8,S=4096,D=1024,E=64,k=2  (M=32768 tokens)
// R8: R7 structure (4 fat waves, 64tok x 128exp/block, fp16x3 MFMA, swizzled LDS)
// with the K-loop barrier rebuilt as raw s_barrier + COUNTED s_waitcnt (T3/T4):
//   per iter: ISSUE_B(t+1) -> CVTW(t+1) -> A-load(t+3) -> compute(t)
//             -> lgkmcnt(0) + vmcnt(2) -> s_barrier
// vmcnt(2) leaves the newest A-prefetch in flight ACROSS the barrier (never
// drain to 0 in-loop). A regs double-buffered in two NAMED sets (no runtime
// indexing); loop runs in parity pairs so set refs are static. Tail peeled.
// Math/addressing verbatim from R7 (verified, absmax 0.00390625).

#define DIM 1024
#define NEXP 64
#define CS 132
#define LOSCALE 2048.0f
#define INV_LOSCALE (1.0f / 2048.0f)
#define ABUF 8192
#define BUFSZ 24576   // A 8KB + B 16KB per buffer

using half8v   = __attribute__((ext_vector_type(8)))  _Float16;
using floatx16 = __attribute__((ext_vector_type(16))) float;

#define MFMA32(a, b, c) __builtin_amdgcn_mfma_f32_32x32x16_f16((a), (b), (c), 0, 0, 0)

#define WAITV2    asm volatile("s_waitcnt vmcnt(2)" ::: "memory")
#define WAITV4    asm volatile("s_waitcnt vmcnt(4)" ::: "memory")
#define WAITV0    asm volatile("s_waitcnt vmcnt(0)" ::: "memory")
#define WAITLGKM0 asm volatile("s_waitcnt lgkmcnt(0)" ::: "memory")
#define SCHED0    __builtin_amdgcn_sched_barrier(0)
#define BAR       __builtin_amdgcn_s_barrier()

__device__ inline void gll16(const void* g, void* l) {
    __builtin_amdgcn_global_load_lds(
        (const __attribute__((address_space(1))) unsigned int*)g,
        (__attribute__((address_space(3))) unsigned int*)l, 16, 0, 0);
}

// ---------------- prep: split weights to fp16 hi/lo, swizzled tile images ----------
__global__ __launch_bounds__(512)
void prep_B(const float* __restrict__ Wl, const float* __restrict__ Wn,
            _Float16* __restrict__ Bp)
{
    const int idx = blockIdx.x * 512 + threadIdx.x;   // 16384 threads
    const int r  = idx >> 7;        // expert row 0..127 (0..63 = Wl, 64..127 = Wn)
    const int c2 = idx & 127;       // 8-float chunk across K=1024
    const float* W = (r < 64) ? (Wl + (size_t)r * DIM) : (Wn + (size_t)(r - 64) * DIM);
    float f[8];
    *(float4*)(f)     = *(const float4*)(W + c2 * 8);
    *(float4*)(f + 4) = *(const float4*)(W + c2 * 8 + 4);
    half8v hi, lo;
#pragma unroll
    for (int i = 0; i < 8; i++) {
        _Float16 hh = (_Float16)f[i];
        hi[i] = hh;
        lo[i] = (_Float16)((f[i] - (float)hh) * LOSCALE);
    }
    const int t = c2 >> 2, cf = c2 & 3, sw = r & 7;
    _Float16* base = Bp + ((size_t)t * 128 + r) * 64;
    *(half8v*)(base + ((cf ^ sw) << 3))       = hi;   // hi chunks 0..3
    *(half8v*)(base + (((4 | cf) ^ sw) << 3)) = lo;   // lo chunks 4..7
}

// ---------------- main fused kernel ------------------------------------------------
__global__ __launch_bounds__(256, 2)
void router_fused(const float* __restrict__ h, const _Float16* __restrict__ Bp,
                  const float* __restrict__ bl, const float* __restrict__ bn,
                  const float* __restrict__ noise,
                  float* __restrict__ outR, float* __restrict__ outIx,
                  float* __restrict__ outF)
{
    __shared__ __align__(16) char lds_raw[2 * BUFSZ];   // 49152 B; Cs needs 33792

    const int tid   = threadIdx.x;           // 0..255
    const int wv    = tid >> 6;              // 0..3
    const int lane  = tid & 63;
    const int row31 = lane & 31;
    const int oct   = lane >> 5;
    const int expg  = wv * 32;               // 0,32,64,96
    const int tok0  = blockIdx.x * 64;

    // ---- A staging map ----
    const int rS = tid >> 2, gS = tid & 3;
    const float* aSrc = h + (size_t)(tok0 + rS) * DIM + gS * 8;
    const int aWrow = rS * 128;
    const int wHi = ((gS ^ (rS & 7)) << 4);
    const int wLo = (((4 | gS) ^ (rS & 7)) << 4);

    // ---- B staging: 4x gll16 per thread (16KB/tile, linear dest) ----
    const _Float16* bSrc = Bp + tid * 8;
    char* dB = lds_raw + ABUF + (tid << 4);

    // ---- fragment offsets (128B rows, 16B-chunk XOR swizzle) ----
    const int rowA0 = row31 * 128;
    const int rowA1 = rowA0 + 32 * 128;
    const int rowB  = ABUF + (expg + row31) * 128;
    const int swA = (row31 & 7) << 4;
    const int swB = ((expg + row31) & 7) << 4;

    floatx16 acc1_0, acc2_0, acc1_1, acc2_1;
#pragma unroll
    for (int i = 0; i < 16; i++) { acc1_0[i] = 0.f; acc2_0[i] = 0.f;
                                   acc1_1[i] = 0.f; acc2_1[i] = 0.f; }

#define CVTW_SET(dst, A0, A1) do {                                             \
        float f_[8] = {(A0).x, (A0).y, (A0).z, (A0).w,                         \
                       (A1).x, (A1).y, (A1).z, (A1).w};                        \
        half8v hi_, lo_;                                                       \
        _Pragma("unroll")                                                      \
        for (int i_ = 0; i_ < 8; i_++) {                                       \
            _Float16 hh_ = (_Float16)f_[i_];                                   \
            hi_[i_] = hh_;                                                     \
            lo_[i_] = (_Float16)((f_[i_] - (float)hh_) * LOSCALE);             \
        }                                                                      \
        *(half8v*)((dst) + aWrow + wHi) = hi_;                                 \
        *(half8v*)((dst) + aWrow + wLo) = lo_;                                 \
    } while (0)

#define ISSUE_B(tt) do {                                                       \
        char* db_ = dB + ((tt) & 1) * BUFSZ;                                   \
        const _Float16* bs_ = bSrc + (size_t)(tt) * 8192;                      \
        gll16(bs_,        db_);                                                \
        gll16(bs_ + 2048, db_ + 4096);                                         \
        gll16(bs_ + 4096, db_ + 8192);                                         \
        gll16(bs_ + 6144, db_ + 12288);                                        \
    } while (0)

#define COMPUTE(BASEP) do {                                                    \
        const char* cbase_ = (const char*)(BASEP);                             \
        _Pragma("unroll")                                                      \
        for (int ks = 0; ks < 2; ks++) {                                       \
            const int hc = (ks * 2 + oct) << 4;                                \
            const half8v aH0 = *(const half8v*)(cbase_ + rowA0 + (hc ^ swA));  \
            const half8v aL0 = *(const half8v*)(cbase_ + rowA0 + ((64|hc)^swA));\
            const half8v aH1 = *(const half8v*)(cbase_ + rowA1 + (hc ^ swA));  \
            const half8v aL1 = *(const half8v*)(cbase_ + rowA1 + ((64|hc)^swA));\
            const half8v bH  = *(const half8v*)(cbase_ + rowB + (hc ^ swB));   \
            const half8v bL  = *(const half8v*)(cbase_ + rowB + ((64|hc)^swB));\
            acc1_0 = MFMA32(aH0, bH, acc1_0);                                  \
            acc2_0 = MFMA32(aH0, bL, acc2_0);                                  \
            acc2_0 = MFMA32(aL0, bH, acc2_0);                                  \
            acc1_1 = MFMA32(aH1, bH, acc1_1);                                  \
            acc2_1 = MFMA32(aH1, bL, acc2_1);                                  \
            acc2_1 = MFMA32(aL1, bH, acc2_1);                                  \
        }                                                                      \
    } while (0)

// Steady-state body: consumes reg set (A0,A1) for tile t+1, reloads it with
// tile t+3.  End wait vmcnt(2): FIFO [A(t+2)x2, B(t+1)x4, A(t+3)x2] -> forces
// A(t+2)+B(t+1) complete, leaves A(t+3) in flight across the barrier.
#define BODY(t, A0, A1) do {                                                   \
        ISSUE_B((t) + 1);                                                      \
        SCHED0;                                                                \
        CVTW_SET(lds_raw + (((t) + 1) & 1) * BUFSZ, A0, A1);                   \
        A0 = *(const float4*)(aSrc + 32 * ((t) + 3));                          \
        A1 = *(const float4*)(aSrc + 32 * ((t) + 3) + 4);                      \
        COMPUTE(lds_raw + ((t) & 1) * BUFSZ);                                  \
        WAITLGKM0; WAITV2; SCHED0;                                             \
        BAR;                                                                   \
    } while (0)

    // ---- prologue: tile0 staged, tiles 1,2 in regs, B(0) in flight ----
    float4 a0e = *(const float4*)(aSrc);          // tile0 (set0)
    float4 a1e = *(const float4*)(aSrc + 4);
    ISSUE_B(0);
    CVTW_SET(lds_raw, a0e, a1e);                  // tile0 -> buf0 (waits its loads)
    SCHED0;
    float4 a0o = *(const float4*)(aSrc + 32);     // tile1 (set1)
    float4 a1o = *(const float4*)(aSrc + 36);
    a0e = *(const float4*)(aSrc + 64);            // tile2 (set0)
    a1e = *(const float4*)(aSrc + 68);
    WAITLGKM0; WAITV4; SCHED0;                    // B(0) done; A1,A2 in flight
    BAR;

    // ---- K loop: t = 0..27 in parity pairs, then t=28, tail peeled ----
    for (int tb = 0; tb < 14; ++tb) {
        const int t0 = 2 * tb;
        BODY(t0,     a0o, a1o);                   // even t: tile t+1 odd -> set1
        BODY(t0 + 1, a0e, a1e);                   // odd  t: tile t+1 even -> set0
    }
    BODY(28, a0o, a1o);                           // loads tile31 -> set1

    // t=29: no more A loads; drain fully (once)
    ISSUE_B(30);
    SCHED0;
    CVTW_SET(lds_raw, a0e, a1e);                  // tile30 -> buf0 (set0)
    COMPUTE(lds_raw + BUFSZ);                     // tile29 from buf1
    WAITLGKM0; WAITV0; SCHED0;
    BAR;
    // t=30
    ISSUE_B(31);
    SCHED0;
    CVTW_SET(lds_raw + BUFSZ, a0o, a1o);          // tile31 -> buf1 (set1)
    COMPUTE(lds_raw);                             // tile30 from buf0
    WAITLGKM0; WAITV0; SCHED0;
    BAR;
    // t=31
    COMPUTE(lds_raw + BUFSZ);                     // tile31 from buf1
    __syncthreads();                              // full drain before Cs overlay

#undef BODY
#undef COMPUTE
#undef ISSUE_B
#undef CVTW_SET

    // ---- Cs overlay: C layout col=lane&31, row=(reg&3)+8*(reg>>2)+4*oct ----
    float* Cs = (float*)lds_raw;
#pragma unroll
    for (int i = 0; i < 16; i++) {
        const int rowt = (i & 3) + 8 * (i >> 2) + 4 * oct;
        Cs[rowt * CS + expg + row31]        = acc1_0[i] + acc2_0[i] * INV_LOSCALE;
        Cs[(32 + rowt) * CS + expg + row31] = acc1_1[i] + acc2_1[i] * INV_LOSCALE;
    }
    __syncthreads();

    // ---- fused epilogue: lane = expert; 16 tokens per wave ----
    const float blv = bl[lane];
    const float bnv = bn[lane];

    for (int t = wv; t < 64; t += 4) {
        const int gt = tok0 + t;
        float xr = Cs[t * CS + lane] + blv;
        float xf = Cs[t * CS + 64 + lane] + bnv;
        float nz = noise[(size_t)gt * NEXP + lane];

        // softplus (matches jax.nn.softplus)
        float stdv = fmaxf(xf, 0.f) + log1pf(expf(-fabsf(xf)));
        float noisy = fmaf(nz, stdv, xr);

        // merged max + argmax#1 (ties -> lowest index, matching lax.top_k)
        float v = noisy; int idx = lane;
#pragma unroll
        for (int o = 32; o > 0; o >>= 1) {
            float ov = __shfl_xor(v, o, 64);
            int   oi = __shfl_xor(idx, o, 64);
            if (ov > v || (ov == v && oi < idx)) { v = ov; idx = oi; }
        }
        const float v1 = v; const int i1 = idx;

        // full softmax over 64 lanes (max == v1)
        float p = expf(noisy - v1);
        float s = p;
#pragma unroll
        for (int o = 32; o > 0; o >>= 1) s += __shfl_xor(s, o, 64);
        float fullp = p / s;

        // argmax #2
        v = (lane == i1) ? -INFINITY : noisy; idx = lane;
#pragma unroll
        for (int o = 32; o > 0; o >>= 1) {
            float ov = __shfl_xor(v, o, 64);
            int   oi = __shfl_xor(idx, o, 64);
            if (ov > v || (ov == v && oi < idx)) { v = ov; idx = oi; }
        }
        const float v2 = v; const int i2 = idx;

        // sparse softmax over {i1,i2}
        float e2 = expf(v2 - v1);
        float den = 1.f + e2;
        float routep = (lane == i1) ? (1.f / den) : ((lane == i2) ? (e2 / den) : 0.f);

        outR[(size_t)gt * NEXP + lane] = routep;
        outF[(size_t)gt * NEXP + lane] = fullp;
        if (lane == 0) {
            outIx[(size_t)gt * 2 + 0] = (float)i1;
            outIx[(size_t)gt * 2 + 1] = (float)i2;
        }
    }
}

extern "C" void kernel_launch(void* const* d_in, const int* in_sizes, int n_in,
                              void* d_out, int out_size, void* d_ws, size_t ws_size,
                              hipStream_t stream) {
    const float* h     = (const float*)d_in[0];
    const float* Wl    = (const float*)d_in[1];
    const float* bl    = (const float*)d_in[2];
    const float* Wn    = (const float*)d_in[3];
    const float* bn    = (const float*)d_in[4];
    const float* noise = (const float*)d_in[5];
    float* out = (float*)d_out;

    const int M = in_sizes[0] / DIM;                 // 32768
    float* outR  = out;                              // [M,64]
    float* outIx = out + (size_t)M * NEXP;           // [M,2]
    float* outF  = outIx + (size_t)M * 2;            // [M,64]

    _Float16* Bp = (_Float16*)d_ws;                  // 512 KiB tile images

    prep_B<<<32, 512, 0, stream>>>(Wl, Wn, Bp);
    router_fused<<<M / 64, 256, 0, stream>>>(h, Bp, bl, bn, noise, outR, outIx, outF);
}